// Round 2
// baseline (489.217 us; speedup 1.0000x reference)
//
#include <hip/hip_runtime.h>
#include <math.h>

// Problem constants
#define BATCH 8
#define SCALE 0.17677669529663687f

// ws layout (float offsets)
#define WS_P    0        // [3][8][256]          final p
#define WS_PP   6144     // [3][8][256][4]       p partials (K-split)
#define WS_QT   30720    // [3][64][256]         folded queries (scaled)
#define WS_QBK  79872    // [3][64]
#define WS_LVL  80064    // [3][8][256]          per-level outputs
#define WS_NUM  86208    // [3][64][256]         attn numerator accum
#define WS_DEN  135360   // [3][64]              attn denominator accum
#define WS_END  135552

// output float4 offsets: out [8,1024] at 0; um0 at 8192; um1 at 67117056; um2 at 83894272
#define UM0_F4 2048u
#define UM1_F4 16779264u
#define UM2_F4 20973568u

typedef float f4 __attribute__((ext_vector_type(4)));

// ---------------- kA1: p partials, K-split by 256 ----------------
__global__ __launch_bounds__(256) void kA1(const float* __restrict__ x,
                                           const float* __restrict__ proj_w,
                                           float* __restrict__ ws) {
    const int i = blockIdx.x, b = blockIdx.y, kk = blockIdx.z;
    const int t = threadIdx.x;
    __shared__ __align__(16) float xs[256];
    xs[t] = x[b * 1024 + kk * 256 + t];
    __syncthreads();
    const f4* w4 = reinterpret_cast<const f4*>(proj_w + (size_t)i * 262144 + (size_t)t * 1024 + kk * 256);
    const f4* x4 = reinterpret_cast<const f4*>(xs);
    float acc = 0.f;
    #pragma unroll 8
    for (int c = 0; c < 64; ++c) {
        f4 w = w4[c], xv = x4[c];
        acc += w.x * xv.x + w.y * xv.y + w.z * xv.z + w.w * xv.w;
    }
    ws[WS_PP + ((size_t)(i * 8 + b) * 256 + t) * 4 + kk] = acc;
}

// ---------------- kA2: p finalize, q, qt (folded+scaled), qbk ----------------
__global__ __launch_bounds__(256) void kA2(const float* __restrict__ proj_b,
                                           const float* __restrict__ inw,
                                           const float* __restrict__ inb,
                                           float* __restrict__ ws) {
    const int i = blockIdx.x, b = blockIdx.y, t = threadIdx.x;
    __shared__ __align__(16) float ps[256];
    __shared__ __align__(16) float qs[256];
    float p = proj_b[i * 256 + t];
    #pragma unroll
    for (int kk = 0; kk < 4; ++kk) p += ws[WS_PP + ((size_t)(i * 8 + b) * 256 + t) * 4 + kk];
    ps[t] = p;
    ws[WS_P + i * 2048 + b * 256 + t] = p;
    __syncthreads();
    // q[t]
    {
        const f4* w4 = reinterpret_cast<const f4*>(inw + (size_t)i * 196608 + (size_t)t * 256);
        const f4* p4 = reinterpret_cast<const f4*>(ps);
        float acc = inb[i * 768 + t];
        #pragma unroll 8
        for (int c = 0; c < 64; ++c) {
            f4 w = w4[c], pv = p4[c];
            acc += w.x * pv.x + w.y * pv.y + w.z * pv.z + w.w * pv.w;
        }
        qs[t] = acc;
    }
    __syncthreads();
    // qt[h, c=t]
    #pragma unroll 1
    for (int h = 0; h < 8; ++h) {
        const float* wk = inw + (size_t)i * 196608 + (size_t)(256 + h * 32) * 256;
        float acc = 0.f;
        #pragma unroll
        for (int d = 0; d < 32; ++d) acc += qs[h * 32 + d] * wk[(size_t)d * 256 + t];
        ws[WS_QT + i * 16384 + (b * 8 + h) * 256 + t] = acc * SCALE;
    }
    if (t < 8) {
        float acc = 0.f;
        #pragma unroll
        for (int d = 0; d < 32; ++d) acc += qs[t * 32 + d] * inb[i * 768 + 256 + t * 32 + d];
        ws[WS_QBK + i * 64 + b * 8 + t] = acc * SCALE;
    }
}

// ---------------- kB: streaming pass, 32 rows/block, 1024 threads ----------------
// lvl0: 1024 blocks, lvl1: 256, lvl2: 64  -> 1344 blocks
__global__ __launch_bounds__(1024, 4) void kB(const float* __restrict__ m0,
                                              const float* __restrict__ m1,
                                              const float* __restrict__ m2,
                                              float* __restrict__ ws,
                                              float* __restrict__ out) {
    const int bx = blockIdx.x;
    int lvl, s0, logS;
    const float* mem;
    size_t outbase4;
    if (bx < 1024)      { lvl = 0; s0 = bx << 5;           logS = 15; mem = m0; outbase4 = UM0_F4; }
    else if (bx < 1280) { lvl = 1; s0 = (bx - 1024) << 5;  logS = 13; mem = m1; outbase4 = UM1_F4; }
    else                { lvl = 2; s0 = (bx - 1280) << 5;  logS = 11; mem = m2; outbase4 = UM2_F4; }

    const int t = threadIdx.x;
    const int bh = t >> 4;      // 0..63
    const int part = t & 15;    // c float4-slice: f4 index = part + 16*g, g<4
    const int c4s = t & 63;     // store-phase column (float4)

    __shared__ __align__(16) float lm[16 * 256];

    // register-resident folded query fragment
    f4 qt4[4];
    {
        const f4* qtp = reinterpret_cast<const f4*>(ws + WS_QT + lvl * 16384 + bh * 256);
        #pragma unroll
        for (int g = 0; g < 4; ++g) qt4[g] = qtp[part + 16 * g];
    }
    const float qbk = ws[WS_QBK + lvl * 64 + bh];

    // register-resident p fragments for the store phase
    f4 pregs[8];
    #pragma unroll
    for (int b = 0; b < 8; ++b)
        pregs[b] = reinterpret_cast<const f4*>(ws + WS_P + lvl * 2048 + b * 256)[c4s];

    f4 nr[4];
    #pragma unroll
    for (int g = 0; g < 4; ++g) nr[g] = 0.f;
    float dn = 0.f;

    f4* out4 = reinterpret_cast<f4*>(out);
    const f4* lm4 = reinterpret_cast<const f4*>(lm);

    for (int tile = 0; tile < 2; ++tile) {
        const int srow = s0 + tile * 16;
        __syncthreads();
        reinterpret_cast<f4*>(lm)[t] = reinterpret_cast<const f4*>(mem + (size_t)srow * 256)[t];
        __syncthreads();

        // issue fused memory-update stores first (drain under compute)
        {
            const f4 mv = lm4[t];
            const int r = t >> 6;
            #pragma unroll
            for (int b = 0; b < 8; ++b) {
                f4 o = mv + pregs[b];
                __builtin_nontemporal_store(o, out4 + outbase4 + ((size_t)((b << logS) + srow + r)) * 64 + c4s);
            }
        }

        // scores + numerator, row fragment register-reused
        for (int r = 0; r < 16; ++r) {
            f4 m4[4];
            #pragma unroll
            for (int g = 0; g < 4; ++g) m4[g] = lm4[r * 64 + part + 16 * g];
            float sc = 0.f;
            #pragma unroll
            for (int g = 0; g < 4; ++g)
                sc += qt4[g].x * m4[g].x + qt4[g].y * m4[g].y + qt4[g].z * m4[g].z + qt4[g].w * m4[g].w;
            sc += __shfl_xor(sc, 1);
            sc += __shfl_xor(sc, 2);
            sc += __shfl_xor(sc, 4);
            sc += __shfl_xor(sc, 8);
            const float e = __expf(sc + qbk);   // scores tiny: no max-subtract needed
            dn += e;
            #pragma unroll
            for (int g = 0; g < 4; ++g) nr[g] += e * m4[g];
        }
    }

    // cross-block reduction
    float* np = ws + WS_NUM + lvl * 16384 + bh * 256 + part * 4;
    #pragma unroll
    for (int g = 0; g < 4; ++g) {
        #pragma unroll
        for (int j = 0; j < 4; ++j) atomicAdd(np + 64 * g + j, nr[g][j]);
    }
    if (part == 0) atomicAdd(ws + WS_DEN + lvl * 64 + bh, dn);
}

// ---------------- kC: attention out + out_proj, 1024 threads ----------------
__global__ __launch_bounds__(1024) void kC(const float* __restrict__ inw,
                                           const float* __restrict__ inb,
                                           const float* __restrict__ outw,
                                           const float* __restrict__ outb,
                                           float* __restrict__ ws) {
    const int i = blockIdx.x, b = blockIdx.y, t = threadIdx.x;
    __shared__ __align__(16) float a[2048];
    __shared__ __align__(16) float ao[256];

    #pragma unroll
    for (int rep = 0; rep < 2; ++rep) {
        const int idx = rep * 1024 + t;
        a[idx] = ws[WS_NUM + i * 16384 + b * 2048 + idx] / ws[WS_DEN + i * 64 + b * 8 + (idx >> 8)];
    }
    __syncthreads();

    const int o = t >> 2, part = t & 3;
    // ao[o] = a[h(o)] . wv[o] + bv[o]
    {
        const f4* w4 = reinterpret_cast<const f4*>(inw + (size_t)i * 196608 + (size_t)(512 + o) * 256) + part * 16;
        const f4* a4 = reinterpret_cast<const f4*>(a + (o >> 5) * 256) + part * 16;
        float acc = 0.f;
        #pragma unroll
        for (int c = 0; c < 16; ++c) {
            f4 w = w4[c], av = a4[c];
            acc += w.x * av.x + w.y * av.y + w.z * av.z + w.w * av.w;
        }
        acc += __shfl_xor(acc, 1);
        acc += __shfl_xor(acc, 2);
        if (part == 0) ao[o] = acc + inb[i * 768 + 512 + o];
    }
    __syncthreads();
    // lvl[o] = ao . outw[i][o] + outb[i][o]
    {
        const f4* w4 = reinterpret_cast<const f4*>(outw + (size_t)i * 65536 + (size_t)o * 256) + part * 16;
        const f4* a4 = reinterpret_cast<const f4*>(ao) + part * 16;
        float acc = 0.f;
        #pragma unroll
        for (int c = 0; c < 16; ++c) {
            f4 w = w4[c], av = a4[c];
            acc += w.x * av.x + w.y * av.y + w.z * av.z + w.w * av.w;
        }
        acc += __shfl_xor(acc, 1);
        acc += __shfl_xor(acc, 2);
        if (part == 0) ws[WS_LVL + i * 2048 + b * 256 + o] = acc + outb[i * 256 + o];
    }
}

// ---------------- kD: merge projection, grid (8,4), 1024 threads ----------------
__global__ __launch_bounds__(1024) void kD(const float* __restrict__ merg_w,
                                           const float* __restrict__ merg_b,
                                           const float* __restrict__ ws,
                                           float* __restrict__ out) {
    const int b = blockIdx.x, quarter = blockIdx.y, t = threadIdx.x;
    __shared__ __align__(16) float comb[768];
    if (t < 768) comb[t] = ws[WS_LVL + (t >> 8) * 2048 + b * 256 + (t & 255)];
    __syncthreads();

    const int j = quarter * 256 + (t >> 2), part = t & 3;
    const f4* w4 = reinterpret_cast<const f4*>(merg_w + (size_t)j * 768) + part * 48;
    const f4* c4 = reinterpret_cast<const f4*>(comb) + part * 48;
    float acc = 0.f;
    #pragma unroll 8
    for (int c = 0; c < 48; ++c) {
        f4 w = w4[c], cv = c4[c];
        acc += w.x * cv.x + w.y * cv.y + w.z * cv.z + w.w * cv.w;
    }
    acc += __shfl_xor(acc, 1);
    acc += __shfl_xor(acc, 2);
    if (part == 0) out[b * 1024 + j] = acc + merg_b[j];
}

extern "C" void kernel_launch(void* const* d_in, const int* in_sizes, int n_in,
                              void* d_out, int out_size, void* d_ws, size_t ws_size,
                              hipStream_t stream) {
    const float* x      = (const float*)d_in[0];
    const float* proj_w = (const float*)d_in[1];
    const float* proj_b = (const float*)d_in[2];
    const float* mem0   = (const float*)d_in[3];
    const float* mem1   = (const float*)d_in[4];
    const float* mem2   = (const float*)d_in[5];
    const float* inw    = (const float*)d_in[6];
    const float* inb    = (const float*)d_in[7];
    const float* outw   = (const float*)d_in[8];
    const float* outb   = (const float*)d_in[9];
    const float* mw     = (const float*)d_in[10];
    const float* mb     = (const float*)d_in[11];
    float* out = (float*)d_out;
    float* ws  = (float*)d_ws;

    hipMemsetAsync(ws + WS_NUM, 0, (size_t)(WS_END - WS_NUM) * sizeof(float), stream);

    kA1<<<dim3(3, 8, 4), 256, 0, stream>>>(x, proj_w, ws);
    kA2<<<dim3(3, 8), 256, 0, stream>>>(proj_b, inw, inb, ws);
    kB<<<1344, 1024, 0, stream>>>(mem0, mem1, mem2, ws, out);
    kC<<<dim3(3, 8), 1024, 0, stream>>>(inw, inb, outw, outb, ws);
    kD<<<dim3(8, 4), 1024, 0, stream>>>(mw, mb, ws, out);
}

// Round 3
// 323.944 us; speedup vs baseline: 1.5102x; 1.5102x over previous
//
#include <hip/hip_runtime.h>
#include <math.h>

// Problem constants
#define BATCH 8
#define SCALE 0.17677669529663687f

// ws layout (float offsets)
#define WS_P    0        // [3][8][256]          final p
#define WS_PP   6144     // [3][8][256][4]       p partials (K-split)
#define WS_QT   30720    // [3][64][256]         folded queries (scaled)
#define WS_QBK  79872    // [3][64]
#define WS_LVL  80064    // [3][8][256]          per-level outputs
#define WS_NUM  86208    // [3][64][256]         attn numerator accum
#define WS_DEN  135360   // [3][64]              attn denominator accum
#define WS_END  135552

// output float4 offsets: out [8,1024] at 0; um0 at 8192; um1 at 67117056; um2 at 83894272
#define UM0_F4 2048u
#define UM1_F4 16779264u
#define UM2_F4 20973568u

typedef float f4 __attribute__((ext_vector_type(4)));

// ---------------- kA1: p partials, K-split by 256 ----------------
__global__ __launch_bounds__(256) void kA1(const float* __restrict__ x,
                                           const float* __restrict__ proj_w,
                                           float* __restrict__ ws) {
    const int i = blockIdx.x, b = blockIdx.y, kk = blockIdx.z;
    const int t = threadIdx.x;
    __shared__ __align__(16) float xs[256];
    xs[t] = x[b * 1024 + kk * 256 + t];
    __syncthreads();
    const f4* w4 = reinterpret_cast<const f4*>(proj_w + (size_t)i * 262144 + (size_t)t * 1024 + kk * 256);
    const f4* x4 = reinterpret_cast<const f4*>(xs);
    float acc = 0.f;
    #pragma unroll 8
    for (int c = 0; c < 64; ++c) {
        f4 w = w4[c], xv = x4[c];
        acc += w.x * xv.x + w.y * xv.y + w.z * xv.z + w.w * xv.w;
    }
    ws[WS_PP + ((size_t)(i * 8 + b) * 256 + t) * 4 + kk] = acc;
}

// ---------------- kA2: p finalize, q, qt (folded+scaled), qbk ----------------
__global__ __launch_bounds__(256) void kA2(const float* __restrict__ proj_b,
                                           const float* __restrict__ inw,
                                           const float* __restrict__ inb,
                                           float* __restrict__ ws) {
    const int i = blockIdx.x, b = blockIdx.y, t = threadIdx.x;
    __shared__ __align__(16) float ps[256];
    __shared__ __align__(16) float qs[256];
    float p = proj_b[i * 256 + t];
    #pragma unroll
    for (int kk = 0; kk < 4; ++kk) p += ws[WS_PP + ((size_t)(i * 8 + b) * 256 + t) * 4 + kk];
    ps[t] = p;
    ws[WS_P + i * 2048 + b * 256 + t] = p;
    __syncthreads();
    // q[t]
    {
        const f4* w4 = reinterpret_cast<const f4*>(inw + (size_t)i * 196608 + (size_t)t * 256);
        const f4* p4 = reinterpret_cast<const f4*>(ps);
        float acc = inb[i * 768 + t];
        #pragma unroll 8
        for (int c = 0; c < 64; ++c) {
            f4 w = w4[c], pv = p4[c];
            acc += w.x * pv.x + w.y * pv.y + w.z * pv.z + w.w * pv.w;
        }
        qs[t] = acc;
    }
    __syncthreads();
    // qt[h, c=t]
    #pragma unroll 1
    for (int h = 0; h < 8; ++h) {
        const float* wk = inw + (size_t)i * 196608 + (size_t)(256 + h * 32) * 256;
        float acc = 0.f;
        #pragma unroll
        for (int d = 0; d < 32; ++d) acc += qs[h * 32 + d] * wk[(size_t)d * 256 + t];
        ws[WS_QT + i * 16384 + (b * 8 + h) * 256 + t] = acc * SCALE;
    }
    if (t < 8) {
        float acc = 0.f;
        #pragma unroll
        for (int d = 0; d < 32; ++d) acc += qs[t * 32 + d] * inb[i * 768 + 256 + t * 32 + d];
        ws[WS_QBK + i * 64 + b * 8 + t] = acc * SCALE;
    }
}

// ---------------- kF: heterogeneous — barrier-free writer blocks + attention blocks ----------------
// grid 2016: bx%3==2 -> attention (672 blocks, 64 rows each);
//            else    -> writer    (1344 blocks, 32 rows each, 8 batches fanout)
__global__ __launch_bounds__(512) void kF(const float* __restrict__ m0,
                                          const float* __restrict__ m1,
                                          const float* __restrict__ m2,
                                          float* __restrict__ ws,
                                          float* __restrict__ out) {
    const int bx = blockIdx.x;
    const int t = threadIdx.x;
    __shared__ __align__(16) f4 lds[2][1024];   // 2 x (16 rows x 64 f4)

    if (bx % 3 == 2) {
        // ================= attention role =================
        const int aid = bx / 3;   // 0..671
        int lvl, s0;
        const float* mem;
        if (aid < 512)      { lvl = 0; s0 = aid << 6;         mem = m0; }
        else if (aid < 640) { lvl = 1; s0 = (aid - 512) << 6; mem = m1; }
        else                { lvl = 2; s0 = (aid - 640) << 6; mem = m2; }

        const int part = t & 15;   // c f4-slice: f4 idx = part + 16g
        const int grp = t >> 4;    // 0..31 -> bh = grp*2 + bl

        f4 qt[2][4];
        const f4* qtb = reinterpret_cast<const f4*>(ws + WS_QT + (size_t)lvl * 16384);
        #pragma unroll
        for (int bl = 0; bl < 2; ++bl)
            #pragma unroll
            for (int g = 0; g < 4; ++g)
                qt[bl][g] = qtb[(size_t)(grp * 2 + bl) * 64 + part + 16 * g];
        float qbk[2];
        #pragma unroll
        for (int bl = 0; bl < 2; ++bl) qbk[bl] = ws[WS_QBK + lvl * 64 + grp * 2 + bl];

        f4 nr[2][4];
        #pragma unroll
        for (int bl = 0; bl < 2; ++bl)
            #pragma unroll
            for (int g = 0; g < 4; ++g) nr[bl][g] = 0.f;
        float dn0 = 0.f, dn1 = 0.f;

        const f4* gm = reinterpret_cast<const f4*>(mem) + (size_t)s0 * 64;
        f4 st[2];
        #pragma unroll
        for (int k = 0; k < 2; ++k) st[k] = gm[t + 512 * k];
        #pragma unroll
        for (int k = 0; k < 2; ++k) lds[0][t + 512 * k] = st[k];
        __syncthreads();

        for (int tile = 0; tile < 4; ++tile) {
            if (tile < 3) {   // issue next tile's global loads early (hide under compute)
                #pragma unroll
                for (int k = 0; k < 2; ++k) st[k] = gm[(tile + 1) * 1024 + t + 512 * k];
            }
            const f4* buf = lds[tile & 1];
            for (int r = 0; r < 16; ++r) {
                f4 m4[4];
                #pragma unroll
                for (int g = 0; g < 4; ++g) m4[g] = buf[r * 64 + part + 16 * g];
                float sc0 = 0.f, sc1 = 0.f;
                #pragma unroll
                for (int g = 0; g < 4; ++g) {
                    sc0 += qt[0][g].x * m4[g].x + qt[0][g].y * m4[g].y + qt[0][g].z * m4[g].z + qt[0][g].w * m4[g].w;
                    sc1 += qt[1][g].x * m4[g].x + qt[1][g].y * m4[g].y + qt[1][g].z * m4[g].z + qt[1][g].w * m4[g].w;
                }
                sc0 += __shfl_xor(sc0, 1); sc1 += __shfl_xor(sc1, 1);
                sc0 += __shfl_xor(sc0, 2); sc1 += __shfl_xor(sc1, 2);
                sc0 += __shfl_xor(sc0, 4); sc1 += __shfl_xor(sc1, 4);
                sc0 += __shfl_xor(sc0, 8); sc1 += __shfl_xor(sc1, 8);
                const float e0 = __expf(sc0 + qbk[0]);   // scores tiny: no max-subtract needed
                const float e1 = __expf(sc1 + qbk[1]);
                dn0 += e0; dn1 += e1;
                #pragma unroll
                for (int g = 0; g < 4; ++g) { nr[0][g] += e0 * m4[g]; nr[1][g] += e1 * m4[g]; }
            }
            if (tile < 3) {
                __syncthreads();
                #pragma unroll
                for (int k = 0; k < 2; ++k) lds[(tile + 1) & 1][t + 512 * k] = st[k];
                __syncthreads();
            }
        }

        #pragma unroll
        for (int bl = 0; bl < 2; ++bl) {
            const int bh = grp * 2 + bl;
            float* np = ws + WS_NUM + (size_t)lvl * 16384 + bh * 256 + part * 4;
            #pragma unroll
            for (int g = 0; g < 4; ++g) {
                #pragma unroll
                for (int j = 0; j < 4; ++j) atomicAdd(np + 64 * g + j, nr[bl][g][j]);
            }
            if (part == 0) atomicAdd(ws + WS_DEN + lvl * 64 + bh, bl == 0 ? dn0 : dn1);
        }
    } else {
        // ================= writer role (no barriers, no LDS use) =================
        const int wid = bx - bx / 3;   // 0..1343
        int lvl, logS;
        size_t row0, ob4;
        const float* mem;
        if (wid < 1024)      { lvl = 0; row0 = (size_t)wid << 5;          ob4 = UM0_F4; logS = 15; mem = m0; }
        else if (wid < 1280) { lvl = 1; row0 = (size_t)(wid - 1024) << 5; ob4 = UM1_F4; logS = 13; mem = m1; }
        else                 { lvl = 2; row0 = (size_t)(wid - 1280) << 5; ob4 = UM2_F4; logS = 11; mem = m2; }

        const int r = t >> 6;    // 0..7
        const int c4 = t & 63;
        f4 pr[8];
        #pragma unroll
        for (int b = 0; b < 8; ++b)
            pr[b] = reinterpret_cast<const f4*>(ws + WS_P + (size_t)lvl * 2048 + b * 256)[c4];

        const f4* mem4 = reinterpret_cast<const f4*>(mem);
        f4* o4 = reinterpret_cast<f4*>(out) + ob4;

        f4 mv[4];
        #pragma unroll
        for (int it = 0; it < 4; ++it)
            mv[it] = mem4[(row0 + it * 8 + r) * 64 + c4];
        #pragma unroll
        for (int it = 0; it < 4; ++it) {
            const size_t row = row0 + it * 8 + r;
            #pragma unroll
            for (int b = 0; b < 8; ++b)
                o4[((size_t)(b << logS) + row) * 64 + c4] = mv[it] + pr[b];
        }
    }
}

// ---------------- kC: attention out + out_proj, 1024 threads ----------------
__global__ __launch_bounds__(1024) void kC(const float* __restrict__ inw,
                                           const float* __restrict__ inb,
                                           const float* __restrict__ outw,
                                           const float* __restrict__ outb,
                                           float* __restrict__ ws) {
    const int i = blockIdx.x, b = blockIdx.y, t = threadIdx.x;
    __shared__ __align__(16) float a[2048];
    __shared__ __align__(16) float ao[256];

    #pragma unroll
    for (int rep = 0; rep < 2; ++rep) {
        const int idx = rep * 1024 + t;
        a[idx] = ws[WS_NUM + i * 16384 + b * 2048 + idx] / ws[WS_DEN + i * 64 + b * 8 + (idx >> 8)];
    }
    __syncthreads();

    const int o = t >> 2, part = t & 3;
    // ao[o] = a[h(o)] . wv[o] + bv[o]
    {
        const f4* w4 = reinterpret_cast<const f4*>(inw + (size_t)i * 196608 + (size_t)(512 + o) * 256) + part * 16;
        const f4* a4 = reinterpret_cast<const f4*>(a + (o >> 5) * 256) + part * 16;
        float acc = 0.f;
        #pragma unroll
        for (int c = 0; c < 16; ++c) {
            f4 w = w4[c], av = a4[c];
            acc += w.x * av.x + w.y * av.y + w.z * av.z + w.w * av.w;
        }
        acc += __shfl_xor(acc, 1);
        acc += __shfl_xor(acc, 2);
        if (part == 0) ao[o] = acc + inb[i * 768 + 512 + o];
    }
    __syncthreads();
    // lvl[o] = ao . outw[i][o] + outb[i][o]
    {
        const f4* w4 = reinterpret_cast<const f4*>(outw + (size_t)i * 65536 + (size_t)o * 256) + part * 16;
        const f4* a4 = reinterpret_cast<const f4*>(ao) + part * 16;
        float acc = 0.f;
        #pragma unroll
        for (int c = 0; c < 16; ++c) {
            f4 w = w4[c], av = a4[c];
            acc += w.x * av.x + w.y * av.y + w.z * av.z + w.w * av.w;
        }
        acc += __shfl_xor(acc, 1);
        acc += __shfl_xor(acc, 2);
        if (part == 0) ws[WS_LVL + i * 2048 + b * 256 + o] = acc + outb[i * 256 + o];
    }
}

// ---------------- kD: merge projection, grid (8,4), 1024 threads ----------------
__global__ __launch_bounds__(1024) void kD(const float* __restrict__ merg_w,
                                           const float* __restrict__ merg_b,
                                           const float* __restrict__ ws,
                                           float* __restrict__ out) {
    const int b = blockIdx.x, quarter = blockIdx.y, t = threadIdx.x;
    __shared__ __align__(16) float comb[768];
    if (t < 768) comb[t] = ws[WS_LVL + (t >> 8) * 2048 + b * 256 + (t & 255)];
    __syncthreads();

    const int j = quarter * 256 + (t >> 2), part = t & 3;
    const f4* w4 = reinterpret_cast<const f4*>(merg_w + (size_t)j * 768) + part * 48;
    const f4* c4 = reinterpret_cast<const f4*>(comb) + part * 48;
    float acc = 0.f;
    #pragma unroll 8
    for (int c = 0; c < 48; ++c) {
        f4 w = w4[c], cv = c4[c];
        acc += w.x * cv.x + w.y * cv.y + w.z * cv.z + w.w * cv.w;
    }
    acc += __shfl_xor(acc, 1);
    acc += __shfl_xor(acc, 2);
    if (part == 0) out[b * 1024 + j] = acc + merg_b[j];
}

extern "C" void kernel_launch(void* const* d_in, const int* in_sizes, int n_in,
                              void* d_out, int out_size, void* d_ws, size_t ws_size,
                              hipStream_t stream) {
    const float* x      = (const float*)d_in[0];
    const float* proj_w = (const float*)d_in[1];
    const float* proj_b = (const float*)d_in[2];
    const float* mem0   = (const float*)d_in[3];
    const float* mem1   = (const float*)d_in[4];
    const float* mem2   = (const float*)d_in[5];
    const float* inw    = (const float*)d_in[6];
    const float* inb    = (const float*)d_in[7];
    const float* outw   = (const float*)d_in[8];
    const float* outb   = (const float*)d_in[9];
    const float* mw     = (const float*)d_in[10];
    const float* mb     = (const float*)d_in[11];
    float* out = (float*)d_out;
    float* ws  = (float*)d_ws;

    hipMemsetAsync(ws + WS_NUM, 0, (size_t)(WS_END - WS_NUM) * sizeof(float), stream);

    kA1<<<dim3(3, 8, 4), 256, 0, stream>>>(x, proj_w, ws);
    kA2<<<dim3(3, 8), 256, 0, stream>>>(proj_b, inw, inb, ws);
    kF<<<2016, 512, 0, stream>>>(mem0, mem1, mem2, ws, out);
    kC<<<dim3(3, 8), 1024, 0, stream>>>(inw, inb, outw, outb, ws);
    kD<<<dim3(8, 4), 1024, 0, stream>>>(mw, mb, ws, out);
}